// Round 11
// baseline (312.818 us; speedup 1.0000x reference)
//
#include <hip/hip_runtime.h>
#include <math.h>

// Projector MPS chain, N=256, S=2, D=64, d=2, B=64, NOUT=129, NIN=127.
// Round 11: round-10 structure + hybrid reg-W in lognorm halves:
// MM1 W-fragments register-prefetched one site ahead (ldbf1), MM2 keeps
// LDS-staged W + wave-local T + 1 barrier/site.

typedef __attribute__((ext_vector_type(8))) short short8;   // 8 bf16
typedef __attribute__((ext_vector_type(4))) float f32x4;

#define MFMA16(a, b, c) __builtin_amdgcn_mfma_f32_16x16x32_bf16(a, b, c, 0, 0, 0)

#define ST 72          // row stride (u16), 144 B rows
#define PL 4608        // 64*ST plane
#define BS 72          // lognorm T: ij-block stride
// lognorm LDS map (u16)
#define L_AL(q) ((q) * PL)                 // 2 planes
#define L_MF(p) (2 * PL + (p) * 18432)     // 2 x [256 rows'][72] staged W
#define L_T     (2 * PL + 2 * 18432)       // [64][296] max = 18944
#define SU_U16  65024                      // 130048 B
// batch LDS map: planes 0 AIN,1 X0,2 X1,3 A0,4 A1,5 T0,6 T1,7 AL/W
#define BPL(i) ((i) * PL)

// ws u16 offsets (after 1024-byte header holding wsf[] f32 results)
#define MINB 0ull
#define MOTB 1040384ull
#define MFIB 3153920ull
#define MFOB 4194304ull
#define WS_U16_TOT 6307840ull
#define EXPFW WS_U16_TOT             // lognorm fwd Al export (4096 u16)
#define EXPBW (WS_U16_TOT + 4096ull) // lognorm adjoint export
#define EXPAF (WS_U16_TOT + 8192ull)          // batch fwd states: 64*4096
#define EXPW  (EXPAF + 262144ull)             // batch bwd states: 64*4096
#define WS_U16_ALL (EXPW + 262144ull)

#define BARRIER() do { asm volatile("s_waitcnt lgkmcnt(0)" ::: "memory"); \
                       __builtin_amdgcn_s_barrier(); } while (0)

__device__ __forceinline__ unsigned pk2(float lo, float hi) {
    unsigned r;
    asm("v_cvt_pk_bf16_f32 %0, %1, %2" : "=v"(r) : "v"(lo), "v"(hi));
    return r;
}
__device__ __forceinline__ ushort f2b(float f) {
    union { float f; unsigned u; } x; x.f = f;
    return (ushort)((x.u + 0x7FFFu + ((x.u >> 16) & 1u)) >> 16);
}
__device__ __forceinline__ float b2f(ushort h) {
    union { unsigned u; float f; } x; x.u = ((unsigned)h) << 16; return x.f;
}
__device__ __forceinline__ short8 ldfrag(const ushort* p) {
    return *reinterpret_cast<const short8*>(p);
}
__device__ __forceinline__ void st64(ushort* p, unsigned lo, unsigned hi) {
    unsigned long long v = ((unsigned long long)hi << 32) | (unsigned long long)lo;
    *reinterpret_cast<unsigned long long*>(p) = v;
}
__device__ __forceinline__ float wave_max(float v) {
#pragma unroll
    for (int off = 32; off > 0; off >>= 1) v = fmaxf(v, __shfl_xor(v, off, 64));
    return v;
}
__device__ __forceinline__ float blk_max(float v, float* scr, int tid) {
    v = wave_max(v);
    BARRIER();
    if ((tid & 63) == 0) scr[tid >> 6] = v;
    BARRIER();
    return fmaxf(fmaxf(scr[0], scr[1]), fmaxf(scr[2], scr[3]));
}
__device__ __forceinline__ short8 pk8(const float* v) {
    union { short8 s; unsigned u[4]; } r;
    r.u[0] = pk2(v[0], v[1]); r.u[1] = pk2(v[2], v[3]);
    r.u[2] = pk2(v[4], v[5]); r.u[3] = pk2(v[6], v[7]);
    return r.s;
}

// ======================= preconversion =======================
// MFIB/MFOB row'-permuted: sites <64: rows'=(ij,second), cols=first (forward);
// sites >=64: transposed gather (adjoint).
__global__ __launch_bounds__(256) void preconv(const float* __restrict__ mi,
                                               const float* __restrict__ mo,
                                               ushort* __restrict__ wsb) {
    __shared__ float lf[16384];
    const int tid = threadIdx.x, blk = blockIdx.x;
    if (blk < 127) {
        const float* src = mi + (size_t)blk * 8192;
#pragma unroll
        for (int n = 0; n < 8; n++)
            *reinterpret_cast<f32x4*>(lf + 4 * (tid + 256 * n)) =
                *reinterpret_cast<const f32x4*>(src + 4 * (tid + 256 * n));
        __syncthreads();
        ushort* d1 = wsb + MINB + (size_t)blk * 8192;   // [l][dd][i] straight
        ushort* d2 = wsb + MFIB + (size_t)blk * 8192;
        const bool adj = (blk >= 64);
#pragma unroll
        for (int n = 0; n < 4; n++) {
            int c = tid + 256 * n;
            float va[8], vb[8];
            int rp = c >> 3, d0 = (c & 7) * 8;
#pragma unroll
            for (int r = 0; r < 8; r++) {
                va[r] = lf[8 * c + r];
                if (!adj) {
                    int msrc = (rp & 63) * 2 + (rp >> 6);
                    vb[r] = lf[(d0 + r) * 128 + msrc];
                } else {
                    vb[r] = lf[(rp & 63) * 128 + (d0 + r) * 2 + (rp >> 6)];
                }
            }
            *reinterpret_cast<short8*>(d1 + 8 * c) = pk8(va);
            *reinterpret_cast<short8*>(d2 + 8 * c) = pk8(vb);
        }
    } else {
        int s = blk - 127;
        const float* src = mo + (size_t)s * 16384;
#pragma unroll
        for (int n = 0; n < 16; n++)
            *reinterpret_cast<f32x4*>(lf + 4 * (tid + 256 * n)) =
                *reinterpret_cast<const f32x4*>(src + 4 * (tid + 256 * n));
        __syncthreads();
        ushort* d1 = wsb + MOTB + (size_t)s * 16384;    // [j][r][dd][i]
        ushort* d2 = wsb + MFOB + (size_t)s * 16384;
        const bool adj = (s >= 64);
#pragma unroll
        for (int n = 0; n < 8; n++) {
            int c = tid + 256 * n;
            float va[8], vb[8];
            int j = c >> 10, r = (c >> 4) & 63, dg = c & 15;
            int rp = c >> 3, d0 = (c & 7) * 8;
#pragma unroll
            for (int q = 0; q < 4; q++)
#pragma unroll
                for (int i = 0; i < 2; i++)
                    va[q * 2 + i] = lf[(dg * 4 + q) * 256 + r * 4 + i * 2 + j];
#pragma unroll
            for (int rr = 0; rr < 8; rr++) {
                if (!adj) {
                    int msrc = (rp & 63) * 4 + (rp >> 6);
                    vb[rr] = lf[(d0 + rr) * 256 + msrc];
                } else {
                    vb[rr] = lf[(rp & 63) * 256 + (d0 + rr) * 4 + (rp >> 6)];
                }
            }
            *reinterpret_cast<short8*>(d1 + 8 * c) = pk8(va);
            *reinterpret_cast<short8*>(d2 + 8 * c) = pk8(vb);
        }
    }
}

// ======================= lognorm matmuls =======================
// prefetch MM1 W-frags into registers (rows 64*tc + 16*w + l15)
__device__ __forceinline__ void ldbf1(short8 (&bf1)[2][4], const ushort* __restrict__ mfg,
                                      int nq, int tid) {
    const int w = tid >> 6, g = (tid >> 4) & 3, l15 = tid & 15;
#pragma unroll
    for (int ks = 0; ks < 2; ks++)
#pragma unroll
        for (int tc = 0; tc < 4; tc++)
            if (tc < nq)
                bf1[ks][tc] = ldfrag(mfg + (size_t)(64 * tc + 16 * w + l15) * 64 + 32 * ks + 8 * g);
}
// MM1 (swapped): C1t[u][m'] = sum_d Al[u][d]*W[m'][d]; T[k=16w+l15][ij*BS+u], scaled.
// REGW=true: W from registers (ldbf1-prefetched); else from LDS L_MF(p).
template <int QW, bool REGW>
__device__ __forceinline__ void ln_mm1(ushort* su, const short8 (&bf1)[2][4],
                                       int q, int p, float sc, int tid) {
    constexpr int TSx = QW * BS + 8;
    const int w = tid >> 6, g = (tid >> 4) & 3, l15 = tid & 15;
    const f32x4 fz = {0.f, 0.f, 0.f, 0.f};
    f32x4 acc[4][QW];
#pragma unroll
    for (int tr = 0; tr < 4; tr++)
#pragma unroll
        for (int tc = 0; tc < QW; tc++) acc[tr][tc] = fz;
#pragma unroll
    for (int ks = 0; ks < 2; ks++) {
        short8 bf[QW];
#pragma unroll
        for (int tc = 0; tc < QW; tc++) {
            if constexpr (REGW) bf[tc] = bf1[ks][tc];
            else bf[tc] = ldfrag(su + L_MF(p) + (64 * tc + 16 * w + l15) * ST + 32 * ks + 8 * g);
        }
#pragma unroll
        for (int tr = 0; tr < 4; tr++) {
            short8 af = ldfrag(su + L_AL(q) + (16 * tr + l15) * ST + 32 * ks + 8 * g);
#pragma unroll
            for (int tc = 0; tc < QW; tc++) acc[tr][tc] = MFMA16(af, bf[tc], acc[tr][tc]);
        }
    }
#pragma unroll
    for (int tr = 0; tr < 4; tr++)
#pragma unroll
        for (int tc = 0; tc < QW; tc++)
            st64(&su[L_T + (16 * w + l15) * TSx + tc * BS + 16 * tr + 4 * g],
                 pk2(acc[tr][tc][0] * sc, acc[tr][tc][1] * sc),
                 pk2(acc[tr][tc][2] * sc, acc[tr][tc][3] * sc));
}
// MM2 (W from LDS, wave-local T): dual-accumulator (parity split) to halve chain depth.
template <int QW>
__device__ __forceinline__ void ln_mm2_lds(ushort* su, int q, int p, int tid, float* red) {
    constexpr int TSx = QW * BS + 8;
    const int w = tid >> 6, g = (tid >> 4) & 3, l15 = tid & 15;
    const f32x4 fz = {0.f, 0.f, 0.f, 0.f};
    f32x4 accA[4], accB[4];
#pragma unroll
    for (int tc = 0; tc < 4; tc++) { accA[tc] = fz; accB[tc] = fz; }
#pragma unroll
    for (int ks2 = 0; ks2 < 2 * QW; ks2++) {
        short8 af = ldfrag(su + L_T + (16 * w + l15) * TSx + (ks2 >> 1) * BS + (ks2 & 1) * 32 + 8 * g);
#pragma unroll
        for (int tc = 0; tc < 4; tc++) {
            short8 bf = ldfrag(su + L_MF(p) + (((ks2 >> 1) << 6) + 16 * tc + l15) * ST +
                               (ks2 & 1) * 32 + 8 * g);
            if (ks2 & 1) accB[tc] = MFMA16(af, bf, accB[tc]);
            else         accA[tc] = MFMA16(af, bf, accA[tc]);
        }
    }
    f32x4 acc[4];
#pragma unroll
    for (int tc = 0; tc < 4; tc++) acc[tc] = accA[tc] + accB[tc];
    float lm = 0.f;
#pragma unroll
    for (int tc = 0; tc < 4; tc++)
#pragma unroll
        for (int r2 = 0; r2 < 4; r2++) lm = fmaxf(lm, fabsf(acc[tc][r2]));
    lm = wave_max(lm);
    if ((tid & 63) == 0) red[w] = lm;
#pragma unroll
    for (int tc = 0; tc < 4; tc++)
        st64(&su[L_AL(q ^ 1) + (16 * tc + l15) * ST + 16 * w + 4 * g],
             pk2(acc[tc][0], acc[tc][1]), pk2(acc[tc][2], acc[tc][3]));
}
// fp32 fallback staging of MFp (permuted rows) — !BFS mono only
template <int QWN>
__device__ __forceinline__ void ln_stage_raw(ushort* su, int pn, const float* __restrict__ Mg, int tid) {
    const int a63 = tid & 63, hi = tid >> 6;
#pragma unroll
    for (int n = 0; n < 4 * QWN; n++) {
        int mb = hi + 4 * n;
        f32x4 v = *reinterpret_cast<const f32x4*>(Mg + 4 * ((size_t)a63 * (16 * QWN) + mb));
#pragma unroll
        for (int c = 0; c < 4; c++) {
            int m = 4 * mb + c;
            int rp = (m & (QWN - 1)) * 64 + (m / QWN);
            su[L_MF(pn) + rp * ST + a63] = f2b(v[c]);
        }
    }
}

// ======================= batch matmuls =======================
// fwd mm1: A=Ain (4 strips), B=X_j (wave strip) -> planes 3,4 hold A_j^T[r][l]
__device__ __forceinline__ void bt_mm1(ushort* su, int tid) {
    const int w = tid >> 6, g = (tid >> 4) & 3, l15 = tid & 15;
    const f32x4 fz = {0.f, 0.f, 0.f, 0.f};
    f32x4 acc[2][4];
#pragma unroll
    for (int j = 0; j < 2; j++)
#pragma unroll
        for (int tr = 0; tr < 4; tr++) acc[j][tr] = fz;
#pragma unroll
    for (int ks = 0; ks < 2; ks++) {
        short8 q0 = ldfrag(su + BPL(1) + (16 * w + l15) * ST + 32 * ks + 8 * g);
        short8 q1 = ldfrag(su + BPL(2) + (16 * w + l15) * ST + 32 * ks + 8 * g);
#pragma unroll
        for (int tr = 0; tr < 4; tr++) {
            short8 pA = ldfrag(su + BPL(0) + (16 * tr + l15) * ST + 32 * ks + 8 * g);
            acc[0][tr] = MFMA16(pA, q0, acc[0][tr]);
            acc[1][tr] = MFMA16(pA, q1, acc[1][tr]);
        }
    }
#pragma unroll
    for (int j = 0; j < 2; j++)
#pragma unroll
        for (int tr = 0; tr < 4; tr++)
            st64(&su[BPL(3 + j) + (16 * w + l15) * ST + 16 * tr + 4 * g],
                 pk2(acc[j][tr][0], acc[j][tr][1]), pk2(acc[j][tr][2], acc[j][tr][3]));
}
// bwd mm1: A=X_j (4 strips), B=Ain (wave strip) -> planes 3,4 hold A_j[l][r]
__device__ __forceinline__ void bw_mm1(ushort* su, int tid) {
    const int w = tid >> 6, g = (tid >> 4) & 3, l15 = tid & 15;
    const f32x4 fz = {0.f, 0.f, 0.f, 0.f};
    f32x4 acc[2][4];
#pragma unroll
    for (int j = 0; j < 2; j++)
#pragma unroll
        for (int tr = 0; tr < 4; tr++) acc[j][tr] = fz;
#pragma unroll
    for (int ks = 0; ks < 2; ks++) {
        short8 bAin = ldfrag(su + BPL(0) + (16 * w + l15) * ST + 32 * ks + 8 * g);
#pragma unroll
        for (int tr = 0; tr < 4; tr++) {
            short8 x0 = ldfrag(su + BPL(1) + (16 * tr + l15) * ST + 32 * ks + 8 * g);
            short8 x1 = ldfrag(su + BPL(2) + (16 * tr + l15) * ST + 32 * ks + 8 * g);
            acc[0][tr] = MFMA16(x0, bAin, acc[0][tr]);
            acc[1][tr] = MFMA16(x1, bAin, acc[1][tr]);
        }
    }
#pragma unroll
    for (int j = 0; j < 2; j++)
#pragma unroll
        for (int tr = 0; tr < 4; tr++)
            st64(&su[BPL(3 + j) + (16 * w + l15) * ST + 16 * tr + 4 * g],
                 pk2(acc[j][tr][0], acc[j][tr][1]), pk2(acc[j][tr][2], acc[j][tr][3]));
}
// mm2: A=plane7 (sym state, 4 strips), B=planes 3,4 (wave strip) -> planes 5,6 (scaled)
__device__ __forceinline__ void bt_mm2(ushort* su, float sc, int tid) {
    const int w = tid >> 6, g = (tid >> 4) & 3, l15 = tid & 15;
    const f32x4 fz = {0.f, 0.f, 0.f, 0.f};
    f32x4 acc[2][4];
#pragma unroll
    for (int j = 0; j < 2; j++)
#pragma unroll
        for (int tr = 0; tr < 4; tr++) acc[j][tr] = fz;
#pragma unroll
    for (int ks = 0; ks < 2; ks++) {
        short8 q0 = ldfrag(su + BPL(3) + (16 * w + l15) * ST + 32 * ks + 8 * g);
        short8 q1 = ldfrag(su + BPL(4) + (16 * w + l15) * ST + 32 * ks + 8 * g);
#pragma unroll
        for (int tr = 0; tr < 4; tr++) {
            short8 pA = ldfrag(su + BPL(7) + (16 * tr + l15) * ST + 32 * ks + 8 * g);
            acc[0][tr] = MFMA16(pA, q0, acc[0][tr]);
            acc[1][tr] = MFMA16(pA, q1, acc[1][tr]);
        }
    }
#pragma unroll
    for (int j = 0; j < 2; j++)
#pragma unroll
        for (int tr = 0; tr < 4; tr++)
            st64(&su[BPL(5 + j) + (16 * w + l15) * ST + 16 * tr + 4 * g],
                 pk2(acc[j][tr][0] * sc, acc[j][tr][1] * sc),
                 pk2(acc[j][tr][2] * sc, acc[j][tr][3] * sc));
}
// mm3: A=planes 5,6 (wave strip), B=planes 3,4 (4 strips) -> plane 7 (sym);
// dual accumulator per j to halve MFMA dependency depth.
__device__ __forceinline__ void bt_mm3(ushort* su, int tid, float* redw) {
    const int w = tid >> 6, g = (tid >> 4) & 3, l15 = tid & 15;
    const f32x4 fz = {0.f, 0.f, 0.f, 0.f};
    f32x4 accJ[2][4];
#pragma unroll
    for (int j = 0; j < 2; j++)
#pragma unroll
        for (int tc = 0; tc < 4; tc++) accJ[j][tc] = fz;
#pragma unroll
    for (int j = 0; j < 2; j++)
#pragma unroll
        for (int ks = 0; ks < 2; ks++) {
            short8 pT = ldfrag(su + BPL(5 + j) + (16 * w + l15) * ST + 32 * ks + 8 * g);
#pragma unroll
            for (int tc = 0; tc < 4; tc++) {
                short8 qf = ldfrag(su + BPL(3 + j) + (16 * tc + l15) * ST + 32 * ks + 8 * g);
                accJ[j][tc] = MFMA16(pT, qf, accJ[j][tc]);
            }
        }
    f32x4 acc[4];
#pragma unroll
    for (int tc = 0; tc < 4; tc++) acc[tc] = accJ[0][tc] + accJ[1][tc];
    float lm = 0.f;
#pragma unroll
    for (int tc = 0; tc < 4; tc++)
#pragma unroll
        for (int r2 = 0; r2 < 4; r2++) lm = fmaxf(lm, fabsf(acc[tc][r2]));
    lm = wave_max(lm);
    if ((tid & 63) == 0) redw[w] = lm;
#pragma unroll
    for (int tc = 0; tc < 4; tc++)
        st64(&su[BPL(7) + (16 * tc + l15) * ST + 16 * w + 4 * g],
             pk2(acc[tc][0], acc[tc][1]), pk2(acc[tc][2], acc[tc][3]));
}

// ======================= main chain kernel =======================
// BFS grid: 0..63 batch fwd, 64..127 batch bwd, 128 lognorm fwd, 129 lognorm adj.
// !BFS grid: 0..63 full batch, 128 full lognorm; others return.
template <bool BFS>
__global__ __launch_bounds__(256, 1) void proj_chain(
    const float* __restrict__ inp, const float* __restrict__ mps_in,
    const float* __restrict__ mps_out, float* __restrict__ wsf,
    ushort* __restrict__ wsb) {
    __shared__ __align__(16) ushort su[SU_U16];
    __shared__ float fsc[176];
    float* red = fsc;
    float* bms = fsc + 16;
    float* A0s = fsc + 32;
    const int tid = threadIdx.x;

    if (blockIdx.x >= 128) {
        short8 bfd[2][4];  // dummy ref for REGW=false template path (never read)
        if constexpr (BFS) {
            // ===== split lognorm halves: 1 barrier/site, hybrid reg-W MM1 =====
            const bool fw = (blockIdx.x == 128);
#pragma unroll
            for (int n = 0; n < 9; n++)
                reinterpret_cast<unsigned*>(su)[tid + 256 * n] = 0u;  // zero Al plane 0
            if (tid == 0) su[0] = (ushort)0x3F80;  // E00
            auto wq = [&](int s) -> int {
                if (fw) return (s & 1) ? 2 : 4;
                int site = 255 - s;
                return (((site & 1) == 0) || site == 255) ? 4 : 2;
            };
            auto wp = [&](int s) -> const ushort* {
                if (fw) return (s & 1) ? wsb + MFIB + (size_t)(s >> 1) * 8192
                                       : wsb + MFOB + (size_t)(s >> 1) * 16384;
                int site = 255 - s;
                if (site == 255) return wsb + MFOB + 128ull * 16384;
                if ((site & 1) == 0) return wsb + MFOB + (size_t)(site >> 1) * 16384;
                return wsb + MFIB + (size_t)(site >> 1) * 8192;
            };
            short8 bfA[2][4], bfB[2][4];
            short8 pf[8];
            {   // stage site 0 into L_MF(0); MM1 regs for site 0; prefetch site 1
                const ushort* s0 = wp(0);
                int q0 = wq(0);
                ldbf1(bfA, s0, q0, tid);
#pragma unroll
                for (int n = 0; n < 8; n++)
                    if (n < 2 * q0) {
                        int c = tid + 256 * n;
                        *reinterpret_cast<short8*>(su + L_MF(0) + (c >> 3) * ST + (c & 7) * 8) =
                            *reinterpret_cast<const short8*>(s0 + (size_t)c * 8);
                    }
                const ushort* s1 = wp(1);
                int q1 = wq(1);
#pragma unroll
                for (int n = 0; n < 8; n++)
                    if (n < 2 * q1)
                        pf[n] = *reinterpret_cast<const short8*>(s1 + (size_t)(tid + 256 * n) * 8);
            }
            BARRIER();
            float accl = 0.f;
            auto lnstep = [&](int s, short8 (&CUR)[2][4], short8 (&NXT)[2][4]) {
                int p = s & 1;
                int qw = wq(s);
                float sc = 1.f;
                if (s > 0) {
                    float* rb = red + p * 8;
                    float m4 = fmaxf(fmaxf(rb[0], rb[1]), fmaxf(rb[2], rb[3]));
                    sc = 1.f / m4;
                    if (tid == 0) accl += logf(m4);
                }
                if (qw == 4) ln_mm1<4, true>(su, CUR, p, p, sc, tid);
                else         ln_mm1<2, true>(su, CUR, p, p, sc, tid);
                if (s + 1 < 128) {
                    ldbf1(NXT, wp(s + 1), wq(s + 1), tid);  // MM1 regs, next site
                    int qn = wq(s + 1);
#pragma unroll
                    for (int n = 0; n < 8; n++)             // stage next W for MM2
                        if (n < 2 * qn) {
                            int c = tid + 256 * n;
                            *reinterpret_cast<short8*>(su + L_MF(p ^ 1) + (c >> 3) * ST + (c & 7) * 8) = pf[n];
                        }
                }
                if (s + 2 < 128) {                          // prefetch site s+2
                    int q2 = wq(s + 2);
                    const ushort* s2 = wp(s + 2);
#pragma unroll
                    for (int n = 0; n < 8; n++)
                        if (n < 2 * q2)
                            pf[n] = *reinterpret_cast<const short8*>(s2 + (size_t)(tid + 256 * n) * 8);
                }
                if (qw == 4) ln_mm2_lds<4>(su, p, p, tid, red + ((s + 1) & 1) * 8);
                else         ln_mm2_lds<2>(su, p, p, tid, red + ((s + 1) & 1) * 8);
                BARRIER();
            };
            for (int t = 0; t < 64; ++t) {
                lnstep(2 * t, bfA, bfB);
                lnstep(2 * t + 1, bfB, bfA);
            }
            size_t base = fw ? EXPFW : EXPBW;
            int row = tid >> 2, c0 = (tid & 3) * 16;
            *reinterpret_cast<short8*>(wsb + base + row * 64 + c0) =
                ldfrag(su + (size_t)row * ST + c0);
            *reinterpret_cast<short8*>(wsb + base + row * 64 + c0 + 8) =
                ldfrag(su + (size_t)row * ST + c0 + 8);
            if (tid == 0) wsf[fw ? 128 : 129] = accl;
            return;
        } else {
            if (blockIdx.x == 129) return;
            // ===== !BFS mono lognorm chain (fp32 staging fallback) =====
#pragma unroll
            for (int n = 0; n < 9; n++)
                reinterpret_cast<unsigned*>(su)[tid + 256 * n] = 0u;
            if (tid == 0) su[0] = (ushort)0x3F80;
            ln_stage_raw<4>(su, 0, mps_out, tid);
            BARRIER();
            float accl = 0.f;
            for (int i = 0; i < 256; i++) {
                int p = i & 1;
                int qw = (((i & 1) == 0) || i == 255) ? 4 : 2;
                float sc = 1.f;
                if (i > 0) {
                    float* rb = red + (i & 1) * 8;
                    float m4 = fmaxf(fmaxf(rb[0], rb[1]), fmaxf(rb[2], rb[3]));
                    sc = 1.f / m4;
                    if (tid == 0) accl += logf(m4);
                }
                if (qw == 4) ln_mm1<4, false>(su, bfd, p, p, sc, tid);
                else         ln_mm1<2, false>(su, bfd, p, p, sc, tid);
                int j = i + 1;
                if (j < 256) {
                    int qn = (((j & 1) == 0) || j == 255) ? 4 : 2;
                    if (qn == 4)
                        ln_stage_raw<4>(su, p ^ 1,
                                        mps_out + (size_t)16384 * ((j == 255) ? 128 : (j >> 1)), tid);
                    else
                        ln_stage_raw<2>(su, p ^ 1, mps_in + (size_t)8192 * (j >> 1), tid);
                }
                if (qw == 4) ln_mm2_lds<4>(su, p, p, tid, red + ((i + 1) & 1) * 8);
                else         ln_mm2_lds<2>(su, p, p, tid, red + ((i + 1) & 1) * 8);
                BARRIER();
            }
            if (tid == 0) { accl += logf(b2f(su[L_AL(0)])); wsf[128] = accl; }
            return;
        }
    }

    // ================= batch chains =================
    if (!BFS && blockIdx.x >= 64) return;
    const bool FWD = (blockIdx.x < 64);
    const int b = blockIdx.x & 63;
    float accl = 0.f;
    short8 pfA[4], pfX[8];

    auto loadpf = [&](int k2) {
        const ushort* mb = wsb + MINB + (size_t)(k2 - 1) * 8192;
        const ushort* xb = wsb + MOTB + (size_t)k2 * 16384;
#pragma unroll
        for (int n = 0; n < 4; n++)
            pfA[n] = *reinterpret_cast<const short8*>(mb + (size_t)(tid + 256 * n) * 8);
#pragma unroll
        for (int n = 0; n < 8; n++)
            pfX[n] = *reinterpret_cast<const short8*>(xb + (size_t)((n >> 2) * 1024 + tid + 256 * (n & 3)) * 8);
    };
    auto stage_bf = [&](int k2) {
        float jv0 = inp[((2 * k2 - 1) * 64 + b) * 2], jv1 = inp[((2 * k2 - 1) * 64 + b) * 2 + 1];
        float ov0 = inp[((2 * k2) * 64 + b) * 2],     ov1 = inp[((2 * k2) * 64 + b) * 2 + 1];
#pragma unroll
        for (int n = 0; n < 4; n++) {
            int c = tid + 256 * n, l = c >> 4, dd0 = (c & 15) * 4;
            short8 r8 = pfA[n];
            float v0 = jv0 * b2f((ushort)r8[0]) + jv1 * b2f((ushort)r8[1]);
            float v1 = jv0 * b2f((ushort)r8[2]) + jv1 * b2f((ushort)r8[3]);
            float v2 = jv0 * b2f((ushort)r8[4]) + jv1 * b2f((ushort)r8[5]);
            float v3 = jv0 * b2f((ushort)r8[6]) + jv1 * b2f((ushort)r8[7]);
            st64(&su[BPL(0) + l * ST + dd0], pk2(v0, v1), pk2(v2, v3));
        }
#pragma unroll
        for (int n = 0; n < 8; n++) {
            int j = n >> 2, c = tid + 256 * (n & 3), r = c >> 4, dd0 = (c & 15) * 4;
            short8 r8 = pfX[n];
            float v0 = ov0 * b2f((ushort)r8[0]) + ov1 * b2f((ushort)r8[1]);
            float v1 = ov0 * b2f((ushort)r8[2]) + ov1 * b2f((ushort)r8[3]);
            float v2 = ov0 * b2f((ushort)r8[4]) + ov1 * b2f((ushort)r8[5]);
            float v3 = ov0 * b2f((ushort)r8[6]) + ov1 * b2f((ushort)r8[7]);
            st64(&su[BPL(1 + j) + r * ST + dd0], pk2(v0, v1), pk2(v2, v3));
        }
    };
    auto stage_f32 = [&](int k2) {
        const int a63 = tid & 63, hi2 = tid >> 6;
        const float* Min = mps_in + (size_t)(k2 - 1) * 8192;
        const float* Mo  = mps_out + (size_t)k2 * 16384;
        float jv0 = inp[((2 * k2 - 1) * 64 + b) * 2], jv1 = inp[((2 * k2 - 1) * 64 + b) * 2 + 1];
        float ov0 = inp[((2 * k2) * 64 + b) * 2],     ov1 = inp[((2 * k2) * 64 + b) * 2 + 1];
#pragma unroll
        for (int n = 0; n < 8; n++) {
            int f = tid + 256 * n, l = f >> 5, dd = (2 * f) & 63;
            f32x4 v = *reinterpret_cast<const f32x4*>(Min + 4 * f);
            *reinterpret_cast<unsigned*>(&su[BPL(0) + l * ST + dd]) =
                pk2(jv0 * v[0] + jv1 * v[1], jv0 * v[2] + jv1 * v[3]);
        }
#pragma unroll
        for (int n = 0; n < 16; n++) {
            int r = hi2 + 4 * n;
            f32x4 v = *reinterpret_cast<const f32x4*>(Mo + 4 * ((size_t)a63 * 64 + r));
            su[BPL(1) + r * ST + a63] = f2b(ov0 * v[0] + ov1 * v[2]);
            su[BPL(2) + r * ST + a63] = f2b(ov0 * v[1] + ov1 * v[3]);
        }
    };

    const int nt = FWD ? 64 : 63;
    auto sidx = [&](int t) { return FWD ? (1 + t) : (127 - t); };

    if constexpr (BFS) loadpf(sidx(0));
    // ---- endpoint site ----
    {
        const float* Ms;
        float v0, v1;
        int rstride;
        if (FWD) { Ms = mps_out; v0 = inp[b * 2]; v1 = inp[b * 2 + 1]; rstride = 4; }
        else { Ms = mps_out + (size_t)128 * 16384; v0 = inp[(255 * 64 + b) * 2];
               v1 = inp[(255 * 64 + b) * 2 + 1]; rstride = 256; }
        if (tid < 128) {
            int r = tid >> 1, jj = tid & 1;
            A0s[tid] = v0 * Ms[r * rstride + jj] + v1 * Ms[r * rstride + 2 + jj];
        }
        BARRIER();
        float vals[16];
        float lm = 0.f;
#pragma unroll
        for (int n = 0; n < 16; n++) {
            int e = tid + 256 * n;
            int u = e >> 6, d2 = e & 63;
            float v = A0s[2 * u] * A0s[2 * d2] + A0s[2 * u + 1] * A0s[2 * d2 + 1];
            vals[n] = v;
            lm = fmaxf(lm, fabsf(v));
        }
        float amax = blk_max(lm, bms, tid);
        if (tid == 0) accl += logf(amax);
        float sc0 = (amax > 0.f) ? 1.f / amax : 0.f;
#pragma unroll
        for (int n = 0; n < 16; n++) {
            int e = tid + 256 * n;
            su[BPL(7) + (e >> 6) * ST + (e & 63)] = f2b(vals[n] * sc0);
        }
    }
    if (tid < 4) red[tid] = 1.0f;  // t=0 parity slots
    const int NT = BFS ? nt : 127;
    if constexpr (BFS) {
        stage_bf(sidx(0));
        if (NT > 1) loadpf(sidx(1));
    } else {
        stage_f32(1);
    }
    BARRIER();

    for (int t = 0; t < NT; t++) {
        int rb = t & 1;
        if (FWD) bt_mm1(su, tid);
        else     bw_mm1(su, tid);
        {
            float* r4 = red + rb * 4;
            float m4 = fmaxf(fmaxf(r4[0], r4[1]), fmaxf(r4[2], r4[3]));
            float sc = 1.f / m4;
            if (tid == 0) accl += logf(m4);
            bt_mm2(su, sc, tid);
        }
        BARRIER();  // B1
        if (t + 1 < NT) {
            if constexpr (BFS) stage_bf(sidx(t + 1));
            else               stage_f32(t + 2);
        }
        bt_mm3(su, tid, red + (rb ^ 1) * 4);
        if constexpr (BFS) { if (t + 2 < NT) loadpf(sidx(t + 2)); }
        BARRIER();  // B2
    }

    if constexpr (BFS) {
        // export state (unscaled; pending max absorbed in combine's log|D1|)
        size_t base = (FWD ? EXPAF : EXPW) + (size_t)b * 4096;
        int row = tid >> 2, c0 = (tid & 3) * 16;
        *reinterpret_cast<short8*>(wsb + base + row * 64 + c0) =
            ldfrag(su + BPL(7) + (size_t)row * ST + c0);
        *reinterpret_cast<short8*>(wsb + base + row * 64 + c0 + 8) =
            ldfrag(su + BPL(7) + (size_t)row * ST + c0 + 8);
        if (tid == 0) wsf[FWD ? b : 64 + b] = accl;
    } else {
        // full-chain final site i=255
        const float* Mo128 = mps_out + (size_t)128 * 16384;
        float fv0 = inp[(255 * 64 + b) * 2], fv1 = inp[(255 * 64 + b) * 2 + 1];
        if (tid < 128) {
            int d2 = tid >> 1, jj = tid & 1;
            A0s[tid] = fv0 * Mo128[d2 * 256 + jj] + fv1 * Mo128[d2 * 256 + 2 + jj];
        }
        BARRIER();
        float part = 0.f;
#pragma unroll
        for (int n = 0; n < 16; n++) {
            int e = tid + 256 * n;
            int d2 = e >> 6, u = e & 63;
            part += b2f(su[BPL(7) + d2 * ST + u]) *
                    (A0s[2 * d2] * A0s[2 * u] + A0s[2 * d2 + 1] * A0s[2 * u + 1]);
        }
#pragma unroll
        for (int off = 32; off > 0; off >>= 1)
            part += __shfl_xor(part, off, 64);
        BARRIER();
        if ((tid & 63) == 0) bms[tid >> 6] = part;
        BARRIER();
        if (tid == 0) {
            float v = bms[0] + bms[1] + bms[2] + bms[3];
            wsf[b] = accl + logf(fabsf(v));
        }
    }
}

__global__ void proj_combine(const float* __restrict__ wsf, const ushort* __restrict__ wsb,
                             float* __restrict__ out, int n, int mode) {
    __shared__ float sred[8];
    const int b = blockIdx.x, tid = threadIdx.x;
    if (b >= n) return;
    if (!mode) {
        if (tid == 0) out[b] = wsf[b] - wsf[128];
        return;
    }
    float d1 = 0.f, d2 = 0.f;
#pragma unroll
    for (int q = 0; q < 16; q++) {
        int e = tid + 256 * q;
        d1 += b2f(wsb[EXPAF + (size_t)b * 4096 + e]) * b2f(wsb[EXPW + (size_t)b * 4096 + e]);
        d2 += b2f(wsb[EXPFW + e]) * b2f(wsb[EXPBW + e]);
    }
#pragma unroll
    for (int off = 32; off > 0; off >>= 1) {
        d1 += __shfl_xor(d1, off, 64);
        d2 += __shfl_xor(d2, off, 64);
    }
    if ((tid & 63) == 0) { sred[tid >> 6] = d1; sred[4 + (tid >> 6)] = d2; }
    __syncthreads();
    if (tid == 0) {
        float D1 = sred[0] + sred[1] + sred[2] + sred[3];
        float D2 = sred[4] + sred[5] + sred[6] + sred[7];
        out[b] = wsf[b] + wsf[64 + b] + logf(fabsf(D1)) -
                 (wsf[128] + wsf[129] + logf(fabsf(D2)));
    }
}

extern "C" void kernel_launch(void* const* d_in, const int* in_sizes, int n_in,
                              void* d_out, int out_size, void* d_ws, size_t ws_size,
                              hipStream_t stream) {
    const float* inp = (const float*)d_in[0];
    const float* mi  = (const float*)d_in[1];
    const float* mo  = (const float*)d_in[2];
    float* wsf = (float*)d_ws;
    ushort* wsb = (ushort*)((char*)d_ws + 1024);
    size_t need = 1024 + WS_U16_ALL * 2;
    int mode = (ws_size >= need) ? 1 : 0;
    if (mode) {
        preconv<<<dim3(256), dim3(256), 0, stream>>>(mi, mo, wsb);
        proj_chain<true><<<dim3(130), dim3(256), 0, stream>>>(inp, mi, mo, wsf, wsb);
    } else {
        proj_chain<false><<<dim3(130), dim3(256), 0, stream>>>(inp, mi, mo, wsf, wsb);
    }
    proj_combine<<<dim3(64), dim3(256), 0, stream>>>(wsf, wsb, (float*)d_out, out_size, mode);
}

// Round 12
// 270.215 us; speedup vs baseline: 1.1577x; 1.1577x over previous
//
#include <hip/hip_runtime.h>
#include <math.h>

// Projector MPS chain, N=256, S=2, D=64, d=2, B=64, NOUT=129, NIN=127.
// Round 12 = revert to round-10 optimum: adjoint-split everywhere; lognorm
// halves use 1-barrier/site structure (LDS-staged W double-buffered via pf
// register prefetch, wave-local T, permuted-row W); dual-accumulator
// depth-halving in ln_mm2 / bt_mm3.

typedef __attribute__((ext_vector_type(8))) short short8;   // 8 bf16
typedef __attribute__((ext_vector_type(4))) float f32x4;

#define MFMA16(a, b, c) __builtin_amdgcn_mfma_f32_16x16x32_bf16(a, b, c, 0, 0, 0)

#define ST 72          // row stride (u16), 144 B rows
#define PL 4608        // 64*ST plane
#define BS 72          // lognorm T: ij-block stride
// lognorm LDS map (u16)
#define L_AL(q) ((q) * PL)                 // 2 planes
#define L_MF(p) (2 * PL + (p) * 18432)     // 2 x [256 rows'][72] staged W
#define L_T     (2 * PL + 2 * 18432)       // [64][296] max = 18944
#define SU_U16  65024                      // 130048 B
// batch LDS map: planes 0 AIN,1 X0,2 X1,3 A0,4 A1,5 T0,6 T1,7 AL/W
#define BPL(i) ((i) * PL)

// ws u16 offsets (after 1024-byte header holding wsf[] f32 results)
#define MINB 0ull
#define MOTB 1040384ull
#define MFIB 3153920ull
#define MFOB 4194304ull
#define WS_U16_TOT 6307840ull
#define EXPFW WS_U16_TOT             // lognorm fwd Al export (4096 u16)
#define EXPBW (WS_U16_TOT + 4096ull) // lognorm adjoint export
#define EXPAF (WS_U16_TOT + 8192ull)          // batch fwd states: 64*4096
#define EXPW  (EXPAF + 262144ull)             // batch bwd states: 64*4096
#define WS_U16_ALL (EXPW + 262144ull)

#define BARRIER() do { asm volatile("s_waitcnt lgkmcnt(0)" ::: "memory"); \
                       __builtin_amdgcn_s_barrier(); } while (0)

__device__ __forceinline__ unsigned pk2(float lo, float hi) {
    unsigned r;
    asm("v_cvt_pk_bf16_f32 %0, %1, %2" : "=v"(r) : "v"(lo), "v"(hi));
    return r;
}
__device__ __forceinline__ ushort f2b(float f) {
    union { float f; unsigned u; } x; x.f = f;
    return (ushort)((x.u + 0x7FFFu + ((x.u >> 16) & 1u)) >> 16);
}
__device__ __forceinline__ float b2f(ushort h) {
    union { unsigned u; float f; } x; x.u = ((unsigned)h) << 16; return x.f;
}
__device__ __forceinline__ short8 ldfrag(const ushort* p) {
    return *reinterpret_cast<const short8*>(p);
}
__device__ __forceinline__ void st64(ushort* p, unsigned lo, unsigned hi) {
    unsigned long long v = ((unsigned long long)hi << 32) | (unsigned long long)lo;
    *reinterpret_cast<unsigned long long*>(p) = v;
}
__device__ __forceinline__ float wave_max(float v) {
#pragma unroll
    for (int off = 32; off > 0; off >>= 1) v = fmaxf(v, __shfl_xor(v, off, 64));
    return v;
}
__device__ __forceinline__ float blk_max(float v, float* scr, int tid) {
    v = wave_max(v);
    BARRIER();
    if ((tid & 63) == 0) scr[tid >> 6] = v;
    BARRIER();
    return fmaxf(fmaxf(scr[0], scr[1]), fmaxf(scr[2], scr[3]));
}
__device__ __forceinline__ short8 pk8(const float* v) {
    union { short8 s; unsigned u[4]; } r;
    r.u[0] = pk2(v[0], v[1]); r.u[1] = pk2(v[2], v[3]);
    r.u[2] = pk2(v[4], v[5]); r.u[3] = pk2(v[6], v[7]);
    return r.s;
}

// ======================= preconversion =======================
// MFIB/MFOB row'-permuted: sites <64: rows'=(ij,second), cols=first (forward);
// sites >=64: transposed gather (adjoint).
__global__ __launch_bounds__(256) void preconv(const float* __restrict__ mi,
                                               const float* __restrict__ mo,
                                               ushort* __restrict__ wsb) {
    __shared__ float lf[16384];
    const int tid = threadIdx.x, blk = blockIdx.x;
    if (blk < 127) {
        const float* src = mi + (size_t)blk * 8192;
#pragma unroll
        for (int n = 0; n < 8; n++)
            *reinterpret_cast<f32x4*>(lf + 4 * (tid + 256 * n)) =
                *reinterpret_cast<const f32x4*>(src + 4 * (tid + 256 * n));
        __syncthreads();
        ushort* d1 = wsb + MINB + (size_t)blk * 8192;   // [l][dd][i] straight
        ushort* d2 = wsb + MFIB + (size_t)blk * 8192;
        const bool adj = (blk >= 64);
#pragma unroll
        for (int n = 0; n < 4; n++) {
            int c = tid + 256 * n;
            float va[8], vb[8];
            int rp = c >> 3, d0 = (c & 7) * 8;
#pragma unroll
            for (int r = 0; r < 8; r++) {
                va[r] = lf[8 * c + r];
                if (!adj) {
                    int msrc = (rp & 63) * 2 + (rp >> 6);
                    vb[r] = lf[(d0 + r) * 128 + msrc];
                } else {
                    vb[r] = lf[(rp & 63) * 128 + (d0 + r) * 2 + (rp >> 6)];
                }
            }
            *reinterpret_cast<short8*>(d1 + 8 * c) = pk8(va);
            *reinterpret_cast<short8*>(d2 + 8 * c) = pk8(vb);
        }
    } else {
        int s = blk - 127;
        const float* src = mo + (size_t)s * 16384;
#pragma unroll
        for (int n = 0; n < 16; n++)
            *reinterpret_cast<f32x4*>(lf + 4 * (tid + 256 * n)) =
                *reinterpret_cast<const f32x4*>(src + 4 * (tid + 256 * n));
        __syncthreads();
        ushort* d1 = wsb + MOTB + (size_t)s * 16384;    // [j][r][dd][i]
        ushort* d2 = wsb + MFOB + (size_t)s * 16384;
        const bool adj = (s >= 64);
#pragma unroll
        for (int n = 0; n < 8; n++) {
            int c = tid + 256 * n;
            float va[8], vb[8];
            int j = c >> 10, r = (c >> 4) & 63, dg = c & 15;
            int rp = c >> 3, d0 = (c & 7) * 8;
#pragma unroll
            for (int q = 0; q < 4; q++)
#pragma unroll
                for (int i = 0; i < 2; i++)
                    va[q * 2 + i] = lf[(dg * 4 + q) * 256 + r * 4 + i * 2 + j];
#pragma unroll
            for (int rr = 0; rr < 8; rr++) {
                if (!adj) {
                    int msrc = (rp & 63) * 4 + (rp >> 6);
                    vb[rr] = lf[(d0 + rr) * 256 + msrc];
                } else {
                    vb[rr] = lf[(rp & 63) * 256 + (d0 + rr) * 4 + (rp >> 6)];
                }
            }
            *reinterpret_cast<short8*>(d1 + 8 * c) = pk8(va);
            *reinterpret_cast<short8*>(d2 + 8 * c) = pk8(vb);
        }
    }
}

// ======================= lognorm matmuls =======================
// MM1 (swapped): C1t[u][m'] = sum_d Al[u][d]*W[m'][d]; T[k=16w+l15][ij*BS+u], scaled.
template <int QW, bool REGW>
__device__ __forceinline__ void ln_mm1(ushort* su, const short8 (&bf1)[2][4],
                                       int q, int p, float sc, int tid) {
    constexpr int TSx = QW * BS + 8;
    const int w = tid >> 6, g = (tid >> 4) & 3, l15 = tid & 15;
    const f32x4 fz = {0.f, 0.f, 0.f, 0.f};
    f32x4 acc[4][QW];
#pragma unroll
    for (int tr = 0; tr < 4; tr++)
#pragma unroll
        for (int tc = 0; tc < QW; tc++) acc[tr][tc] = fz;
#pragma unroll
    for (int ks = 0; ks < 2; ks++) {
        short8 bf[QW];
#pragma unroll
        for (int tc = 0; tc < QW; tc++) {
            if constexpr (REGW) bf[tc] = bf1[ks][tc];
            else bf[tc] = ldfrag(su + L_MF(p) + (64 * tc + 16 * w + l15) * ST + 32 * ks + 8 * g);
        }
#pragma unroll
        for (int tr = 0; tr < 4; tr++) {
            short8 af = ldfrag(su + L_AL(q) + (16 * tr + l15) * ST + 32 * ks + 8 * g);
#pragma unroll
            for (int tc = 0; tc < QW; tc++) acc[tr][tc] = MFMA16(af, bf[tc], acc[tr][tc]);
        }
    }
#pragma unroll
    for (int tr = 0; tr < 4; tr++)
#pragma unroll
        for (int tc = 0; tc < QW; tc++)
            st64(&su[L_T + (16 * w + l15) * TSx + tc * BS + 16 * tr + 4 * g],
                 pk2(acc[tr][tc][0] * sc, acc[tr][tc][1] * sc),
                 pk2(acc[tr][tc][2] * sc, acc[tr][tc][3] * sc));
}
// MM2 (W from LDS, wave-local T): dual-accumulator (parity split) to halve chain depth.
template <int QW>
__device__ __forceinline__ void ln_mm2_lds(ushort* su, int q, int p, int tid, float* red) {
    constexpr int TSx = QW * BS + 8;
    const int w = tid >> 6, g = (tid >> 4) & 3, l15 = tid & 15;
    const f32x4 fz = {0.f, 0.f, 0.f, 0.f};
    f32x4 accA[4], accB[4];
#pragma unroll
    for (int tc = 0; tc < 4; tc++) { accA[tc] = fz; accB[tc] = fz; }
#pragma unroll
    for (int ks2 = 0; ks2 < 2 * QW; ks2++) {
        short8 af = ldfrag(su + L_T + (16 * w + l15) * TSx + (ks2 >> 1) * BS + (ks2 & 1) * 32 + 8 * g);
#pragma unroll
        for (int tc = 0; tc < 4; tc++) {
            short8 bf = ldfrag(su + L_MF(p) + (((ks2 >> 1) << 6) + 16 * tc + l15) * ST +
                               (ks2 & 1) * 32 + 8 * g);
            if (ks2 & 1) accB[tc] = MFMA16(af, bf, accB[tc]);
            else         accA[tc] = MFMA16(af, bf, accA[tc]);
        }
    }
    f32x4 acc[4];
#pragma unroll
    for (int tc = 0; tc < 4; tc++) acc[tc] = accA[tc] + accB[tc];
    float lm = 0.f;
#pragma unroll
    for (int tc = 0; tc < 4; tc++)
#pragma unroll
        for (int r2 = 0; r2 < 4; r2++) lm = fmaxf(lm, fabsf(acc[tc][r2]));
    lm = wave_max(lm);
    if ((tid & 63) == 0) red[w] = lm;
#pragma unroll
    for (int tc = 0; tc < 4; tc++)
        st64(&su[L_AL(q ^ 1) + (16 * tc + l15) * ST + 16 * w + 4 * g],
             pk2(acc[tc][0], acc[tc][1]), pk2(acc[tc][2], acc[tc][3]));
}
// fp32 fallback staging of MFp (permuted rows) — !BFS mono only
template <int QWN>
__device__ __forceinline__ void ln_stage_raw(ushort* su, int pn, const float* __restrict__ Mg, int tid) {
    const int a63 = tid & 63, hi = tid >> 6;
#pragma unroll
    for (int n = 0; n < 4 * QWN; n++) {
        int mb = hi + 4 * n;
        f32x4 v = *reinterpret_cast<const f32x4*>(Mg + 4 * ((size_t)a63 * (16 * QWN) + mb));
#pragma unroll
        for (int c = 0; c < 4; c++) {
            int m = 4 * mb + c;
            int rp = (m & (QWN - 1)) * 64 + (m / QWN);
            su[L_MF(pn) + rp * ST + a63] = f2b(v[c]);
        }
    }
}

// ======================= batch matmuls =======================
// fwd mm1: A=Ain (4 strips), B=X_j (wave strip) -> planes 3,4 hold A_j^T[r][l]
__device__ __forceinline__ void bt_mm1(ushort* su, int tid) {
    const int w = tid >> 6, g = (tid >> 4) & 3, l15 = tid & 15;
    const f32x4 fz = {0.f, 0.f, 0.f, 0.f};
    f32x4 acc[2][4];
#pragma unroll
    for (int j = 0; j < 2; j++)
#pragma unroll
        for (int tr = 0; tr < 4; tr++) acc[j][tr] = fz;
#pragma unroll
    for (int ks = 0; ks < 2; ks++) {
        short8 q0 = ldfrag(su + BPL(1) + (16 * w + l15) * ST + 32 * ks + 8 * g);
        short8 q1 = ldfrag(su + BPL(2) + (16 * w + l15) * ST + 32 * ks + 8 * g);
#pragma unroll
        for (int tr = 0; tr < 4; tr++) {
            short8 pA = ldfrag(su + BPL(0) + (16 * tr + l15) * ST + 32 * ks + 8 * g);
            acc[0][tr] = MFMA16(pA, q0, acc[0][tr]);
            acc[1][tr] = MFMA16(pA, q1, acc[1][tr]);
        }
    }
#pragma unroll
    for (int j = 0; j < 2; j++)
#pragma unroll
        for (int tr = 0; tr < 4; tr++)
            st64(&su[BPL(3 + j) + (16 * w + l15) * ST + 16 * tr + 4 * g],
                 pk2(acc[j][tr][0], acc[j][tr][1]), pk2(acc[j][tr][2], acc[j][tr][3]));
}
// bwd mm1: A=X_j (4 strips), B=Ain (wave strip) -> planes 3,4 hold A_j[l][r]
__device__ __forceinline__ void bw_mm1(ushort* su, int tid) {
    const int w = tid >> 6, g = (tid >> 4) & 3, l15 = tid & 15;
    const f32x4 fz = {0.f, 0.f, 0.f, 0.f};
    f32x4 acc[2][4];
#pragma unroll
    for (int j = 0; j < 2; j++)
#pragma unroll
        for (int tr = 0; tr < 4; tr++) acc[j][tr] = fz;
#pragma unroll
    for (int ks = 0; ks < 2; ks++) {
        short8 bAin = ldfrag(su + BPL(0) + (16 * w + l15) * ST + 32 * ks + 8 * g);
#pragma unroll
        for (int tr = 0; tr < 4; tr++) {
            short8 x0 = ldfrag(su + BPL(1) + (16 * tr + l15) * ST + 32 * ks + 8 * g);
            short8 x1 = ldfrag(su + BPL(2) + (16 * tr + l15) * ST + 32 * ks + 8 * g);
            acc[0][tr] = MFMA16(x0, bAin, acc[0][tr]);
            acc[1][tr] = MFMA16(x1, bAin, acc[1][tr]);
        }
    }
#pragma unroll
    for (int j = 0; j < 2; j++)
#pragma unroll
        for (int tr = 0; tr < 4; tr++)
            st64(&su[BPL(3 + j) + (16 * w + l15) * ST + 16 * tr + 4 * g],
                 pk2(acc[j][tr][0], acc[j][tr][1]), pk2(acc[j][tr][2], acc[j][tr][3]));
}
// mm2: A=plane7 (sym state, 4 strips), B=planes 3,4 (wave strip) -> planes 5,6 (scaled)
__device__ __forceinline__ void bt_mm2(ushort* su, float sc, int tid) {
    const int w = tid >> 6, g = (tid >> 4) & 3, l15 = tid & 15;
    const f32x4 fz = {0.f, 0.f, 0.f, 0.f};
    f32x4 acc[2][4];
#pragma unroll
    for (int j = 0; j < 2; j++)
#pragma unroll
        for (int tr = 0; tr < 4; tr++) acc[j][tr] = fz;
#pragma unroll
    for (int ks = 0; ks < 2; ks++) {
        short8 q0 = ldfrag(su + BPL(3) + (16 * w + l15) * ST + 32 * ks + 8 * g);
        short8 q1 = ldfrag(su + BPL(4) + (16 * w + l15) * ST + 32 * ks + 8 * g);
#pragma unroll
        for (int tr = 0; tr < 4; tr++) {
            short8 pA = ldfrag(su + BPL(7) + (16 * tr + l15) * ST + 32 * ks + 8 * g);
            acc[0][tr] = MFMA16(pA, q0, acc[0][tr]);
            acc[1][tr] = MFMA16(pA, q1, acc[1][tr]);
        }
    }
#pragma unroll
    for (int j = 0; j < 2; j++)
#pragma unroll
        for (int tr = 0; tr < 4; tr++)
            st64(&su[BPL(5 + j) + (16 * w + l15) * ST + 16 * tr + 4 * g],
                 pk2(acc[j][tr][0] * sc, acc[j][tr][1] * sc),
                 pk2(acc[j][tr][2] * sc, acc[j][tr][3] * sc));
}
// mm3: A=planes 5,6 (wave strip), B=planes 3,4 (4 strips) -> plane 7 (sym);
// dual accumulator per j to halve MFMA dependency depth.
__device__ __forceinline__ void bt_mm3(ushort* su, int tid, float* redw) {
    const int w = tid >> 6, g = (tid >> 4) & 3, l15 = tid & 15;
    const f32x4 fz = {0.f, 0.f, 0.f, 0.f};
    f32x4 accJ[2][4];
#pragma unroll
    for (int j = 0; j < 2; j++)
#pragma unroll
        for (int tc = 0; tc < 4; tc++) accJ[j][tc] = fz;
#pragma unroll
    for (int j = 0; j < 2; j++)
#pragma unroll
        for (int ks = 0; ks < 2; ks++) {
            short8 pT = ldfrag(su + BPL(5 + j) + (16 * w + l15) * ST + 32 * ks + 8 * g);
#pragma unroll
            for (int tc = 0; tc < 4; tc++) {
                short8 qf = ldfrag(su + BPL(3 + j) + (16 * tc + l15) * ST + 32 * ks + 8 * g);
                accJ[j][tc] = MFMA16(pT, qf, accJ[j][tc]);
            }
        }
    f32x4 acc[4];
#pragma unroll
    for (int tc = 0; tc < 4; tc++) acc[tc] = accJ[0][tc] + accJ[1][tc];
    float lm = 0.f;
#pragma unroll
    for (int tc = 0; tc < 4; tc++)
#pragma unroll
        for (int r2 = 0; r2 < 4; r2++) lm = fmaxf(lm, fabsf(acc[tc][r2]));
    lm = wave_max(lm);
    if ((tid & 63) == 0) redw[w] = lm;
#pragma unroll
    for (int tc = 0; tc < 4; tc++)
        st64(&su[BPL(7) + (16 * tc + l15) * ST + 16 * w + 4 * g],
             pk2(acc[tc][0], acc[tc][1]), pk2(acc[tc][2], acc[tc][3]));
}

// ======================= main chain kernel =======================
// BFS grid: 0..63 batch fwd, 64..127 batch bwd, 128 lognorm fwd, 129 lognorm adj.
// !BFS grid: 0..63 full batch, 128 full lognorm; others return.
template <bool BFS>
__global__ __launch_bounds__(256, 1) void proj_chain(
    const float* __restrict__ inp, const float* __restrict__ mps_in,
    const float* __restrict__ mps_out, float* __restrict__ wsf,
    ushort* __restrict__ wsb) {
    __shared__ __align__(16) ushort su[SU_U16];
    __shared__ float fsc[176];
    float* red = fsc;
    float* bms = fsc + 16;
    float* A0s = fsc + 32;
    const int tid = threadIdx.x;

    if (blockIdx.x >= 128) {
        short8 bfd[2][4];  // dummy ref for REGW=false template path (never read)
        if constexpr (BFS) {
            // ===== split lognorm halves, round-6 1-barrier/site structure =====
            const bool fw = (blockIdx.x == 128);
#pragma unroll
            for (int n = 0; n < 9; n++)
                reinterpret_cast<unsigned*>(su)[tid + 256 * n] = 0u;  // zero Al plane 0
            if (tid == 0) su[0] = (ushort)0x3F80;  // E00
            auto wq = [&](int s) -> int {
                if (fw) return (s & 1) ? 2 : 4;
                int site = 255 - s;
                return (((site & 1) == 0) || site == 255) ? 4 : 2;
            };
            auto wp = [&](int s) -> const ushort* {
                if (fw) return (s & 1) ? wsb + MFIB + (size_t)(s >> 1) * 8192
                                       : wsb + MFOB + (size_t)(s >> 1) * 16384;
                int site = 255 - s;
                if (site == 255) return wsb + MFOB + 128ull * 16384;
                if ((site & 1) == 0) return wsb + MFOB + (size_t)(site >> 1) * 16384;
                return wsb + MFIB + (size_t)(site >> 1) * 8192;
            };
            short8 pf[8];
            {   // stage site 0 into L_MF(0); prefetch site 1 into pf
                const ushort* s0 = wp(0);
                int q0 = wq(0);
#pragma unroll
                for (int n = 0; n < 8; n++)
                    if (n < 2 * q0) {
                        int c = tid + 256 * n;
                        *reinterpret_cast<short8*>(su + L_MF(0) + (c >> 3) * ST + (c & 7) * 8) =
                            *reinterpret_cast<const short8*>(s0 + (size_t)c * 8);
                    }
                const ushort* s1 = wp(1);
                int q1 = wq(1);
#pragma unroll
                for (int n = 0; n < 8; n++)
                    if (n < 2 * q1)
                        pf[n] = *reinterpret_cast<const short8*>(s1 + (size_t)(tid + 256 * n) * 8);
            }
            BARRIER();
            float accl = 0.f;
            for (int s = 0; s < 128; s++) {
                int p = s & 1;
                int qw = wq(s);
                float sc = 1.f;
                if (s > 0) {
                    float* rb = red + p * 8;
                    float m4 = fmaxf(fmaxf(rb[0], rb[1]), fmaxf(rb[2], rb[3]));
                    sc = 1.f / m4;
                    if (tid == 0) accl += logf(m4);
                }
                if (qw == 4) ln_mm1<4, false>(su, bfd, p, p, sc, tid);
                else         ln_mm1<2, false>(su, bfd, p, p, sc, tid);
                if (s + 1 < 128) {  // stage site s+1 (in pf) into other MF buffer
                    int qn = wq(s + 1);
#pragma unroll
                    for (int n = 0; n < 8; n++)
                        if (n < 2 * qn) {
                            int c = tid + 256 * n;
                            *reinterpret_cast<short8*>(su + L_MF(p ^ 1) + (c >> 3) * ST + (c & 7) * 8) = pf[n];
                        }
                }
                if (s + 2 < 128) {  // prefetch site s+2
                    int q2 = wq(s + 2);
                    const ushort* s2 = wp(s + 2);
#pragma unroll
                    for (int n = 0; n < 8; n++)
                        if (n < 2 * q2)
                            pf[n] = *reinterpret_cast<const short8*>(s2 + (size_t)(tid + 256 * n) * 8);
                }
                if (qw == 4) ln_mm2_lds<4>(su, p, p, tid, red + ((s + 1) & 1) * 8);
                else         ln_mm2_lds<2>(su, p, p, tid, red + ((s + 1) & 1) * 8);
                BARRIER();
            }
            size_t base = fw ? EXPFW : EXPBW;
            int row = tid >> 2, c0 = (tid & 3) * 16;
            *reinterpret_cast<short8*>(wsb + base + row * 64 + c0) =
                ldfrag(su + (size_t)row * ST + c0);
            *reinterpret_cast<short8*>(wsb + base + row * 64 + c0 + 8) =
                ldfrag(su + (size_t)row * ST + c0 + 8);
            if (tid == 0) wsf[fw ? 128 : 129] = accl;
            return;
        } else {
            if (blockIdx.x == 129) return;
            // ===== !BFS mono lognorm chain (fp32 staging fallback) =====
#pragma unroll
            for (int n = 0; n < 9; n++)
                reinterpret_cast<unsigned*>(su)[tid + 256 * n] = 0u;
            if (tid == 0) su[0] = (ushort)0x3F80;
            ln_stage_raw<4>(su, 0, mps_out, tid);
            BARRIER();
            float accl = 0.f;
            for (int i = 0; i < 256; i++) {
                int p = i & 1;
                int qw = (((i & 1) == 0) || i == 255) ? 4 : 2;
                float sc = 1.f;
                if (i > 0) {
                    float* rb = red + (i & 1) * 8;
                    float m4 = fmaxf(fmaxf(rb[0], rb[1]), fmaxf(rb[2], rb[3]));
                    sc = 1.f / m4;
                    if (tid == 0) accl += logf(m4);
                }
                if (qw == 4) ln_mm1<4, false>(su, bfd, p, p, sc, tid);
                else         ln_mm1<2, false>(su, bfd, p, p, sc, tid);
                int j = i + 1;
                if (j < 256) {
                    int qn = (((j & 1) == 0) || j == 255) ? 4 : 2;
                    if (qn == 4)
                        ln_stage_raw<4>(su, p ^ 1,
                                        mps_out + (size_t)16384 * ((j == 255) ? 128 : (j >> 1)), tid);
                    else
                        ln_stage_raw<2>(su, p ^ 1, mps_in + (size_t)8192 * (j >> 1), tid);
                }
                if (qw == 4) ln_mm2_lds<4>(su, p, p, tid, red + ((i + 1) & 1) * 8);
                else         ln_mm2_lds<2>(su, p, p, tid, red + ((i + 1) & 1) * 8);
                BARRIER();
            }
            if (tid == 0) { accl += logf(b2f(su[L_AL(0)])); wsf[128] = accl; }
            return;
        }
    }

    // ================= batch chains =================
    if (!BFS && blockIdx.x >= 64) return;
    const bool FWD = (blockIdx.x < 64);
    const int b = blockIdx.x & 63;
    float accl = 0.f;
    short8 pfA[4], pfX[8];

    auto loadpf = [&](int k2) {
        const ushort* mb = wsb + MINB + (size_t)(k2 - 1) * 8192;
        const ushort* xb = wsb + MOTB + (size_t)k2 * 16384;
#pragma unroll
        for (int n = 0; n < 4; n++)
            pfA[n] = *reinterpret_cast<const short8*>(mb + (size_t)(tid + 256 * n) * 8);
#pragma unroll
        for (int n = 0; n < 8; n++)
            pfX[n] = *reinterpret_cast<const short8*>(xb + (size_t)((n >> 2) * 1024 + tid + 256 * (n & 3)) * 8);
    };
    auto stage_bf = [&](int k2) {
        float jv0 = inp[((2 * k2 - 1) * 64 + b) * 2], jv1 = inp[((2 * k2 - 1) * 64 + b) * 2 + 1];
        float ov0 = inp[((2 * k2) * 64 + b) * 2],     ov1 = inp[((2 * k2) * 64 + b) * 2 + 1];
#pragma unroll
        for (int n = 0; n < 4; n++) {
            int c = tid + 256 * n, l = c >> 4, dd0 = (c & 15) * 4;
            short8 r8 = pfA[n];
            float v0 = jv0 * b2f((ushort)r8[0]) + jv1 * b2f((ushort)r8[1]);
            float v1 = jv0 * b2f((ushort)r8[2]) + jv1 * b2f((ushort)r8[3]);
            float v2 = jv0 * b2f((ushort)r8[4]) + jv1 * b2f((ushort)r8[5]);
            float v3 = jv0 * b2f((ushort)r8[6]) + jv1 * b2f((ushort)r8[7]);
            st64(&su[BPL(0) + l * ST + dd0], pk2(v0, v1), pk2(v2, v3));
        }
#pragma unroll
        for (int n = 0; n < 8; n++) {
            int j = n >> 2, c = tid + 256 * (n & 3), r = c >> 4, dd0 = (c & 15) * 4;
            short8 r8 = pfX[n];
            float v0 = ov0 * b2f((ushort)r8[0]) + ov1 * b2f((ushort)r8[1]);
            float v1 = ov0 * b2f((ushort)r8[2]) + ov1 * b2f((ushort)r8[3]);
            float v2 = ov0 * b2f((ushort)r8[4]) + ov1 * b2f((ushort)r8[5]);
            float v3 = ov0 * b2f((ushort)r8[6]) + ov1 * b2f((ushort)r8[7]);
            st64(&su[BPL(1 + j) + r * ST + dd0], pk2(v0, v1), pk2(v2, v3));
        }
    };
    auto stage_f32 = [&](int k2) {
        const int a63 = tid & 63, hi2 = tid >> 6;
        const float* Min = mps_in + (size_t)(k2 - 1) * 8192;
        const float* Mo  = mps_out + (size_t)k2 * 16384;
        float jv0 = inp[((2 * k2 - 1) * 64 + b) * 2], jv1 = inp[((2 * k2 - 1) * 64 + b) * 2 + 1];
        float ov0 = inp[((2 * k2) * 64 + b) * 2],     ov1 = inp[((2 * k2) * 64 + b) * 2 + 1];
#pragma unroll
        for (int n = 0; n < 8; n++) {
            int f = tid + 256 * n, l = f >> 5, dd = (2 * f) & 63;
            f32x4 v = *reinterpret_cast<const f32x4*>(Min + 4 * f);
            *reinterpret_cast<unsigned*>(&su[BPL(0) + l * ST + dd]) =
                pk2(jv0 * v[0] + jv1 * v[1], jv0 * v[2] + jv1 * v[3]);
        }
#pragma unroll
        for (int n = 0; n < 16; n++) {
            int r = hi2 + 4 * n;
            f32x4 v = *reinterpret_cast<const f32x4*>(Mo + 4 * ((size_t)a63 * 64 + r));
            su[BPL(1) + r * ST + a63] = f2b(ov0 * v[0] + ov1 * v[2]);
            su[BPL(2) + r * ST + a63] = f2b(ov0 * v[1] + ov1 * v[3]);
        }
    };

    const int nt = FWD ? 64 : 63;
    auto sidx = [&](int t) { return FWD ? (1 + t) : (127 - t); };

    if constexpr (BFS) loadpf(sidx(0));
    // ---- endpoint site ----
    {
        const float* Ms;
        float v0, v1;
        int rstride;
        if (FWD) { Ms = mps_out; v0 = inp[b * 2]; v1 = inp[b * 2 + 1]; rstride = 4; }
        else { Ms = mps_out + (size_t)128 * 16384; v0 = inp[(255 * 64 + b) * 2];
               v1 = inp[(255 * 64 + b) * 2 + 1]; rstride = 256; }
        if (tid < 128) {
            int r = tid >> 1, jj = tid & 1;
            A0s[tid] = v0 * Ms[r * rstride + jj] + v1 * Ms[r * rstride + 2 + jj];
        }
        BARRIER();
        float vals[16];
        float lm = 0.f;
#pragma unroll
        for (int n = 0; n < 16; n++) {
            int e = tid + 256 * n;
            int u = e >> 6, d2 = e & 63;
            float v = A0s[2 * u] * A0s[2 * d2] + A0s[2 * u + 1] * A0s[2 * d2 + 1];
            vals[n] = v;
            lm = fmaxf(lm, fabsf(v));
        }
        float amax = blk_max(lm, bms, tid);
        if (tid == 0) accl += logf(amax);
        float sc0 = (amax > 0.f) ? 1.f / amax : 0.f;
#pragma unroll
        for (int n = 0; n < 16; n++) {
            int e = tid + 256 * n;
            su[BPL(7) + (e >> 6) * ST + (e & 63)] = f2b(vals[n] * sc0);
        }
    }
    if (tid < 4) red[tid] = 1.0f;  // t=0 parity slots
    const int NT = BFS ? nt : 127;
    if constexpr (BFS) {
        stage_bf(sidx(0));
        if (NT > 1) loadpf(sidx(1));
    } else {
        stage_f32(1);
    }
    BARRIER();

    for (int t = 0; t < NT; t++) {
        int rb = t & 1;
        if (FWD) bt_mm1(su, tid);
        else     bw_mm1(su, tid);
        {
            float* r4 = red + rb * 4;
            float m4 = fmaxf(fmaxf(r4[0], r4[1]), fmaxf(r4[2], r4[3]));
            float sc = 1.f / m4;
            if (tid == 0) accl += logf(m4);
            bt_mm2(su, sc, tid);
        }
        BARRIER();  // B1
        if (t + 1 < NT) {
            if constexpr (BFS) stage_bf(sidx(t + 1));
            else               stage_f32(t + 2);
        }
        bt_mm3(su, tid, red + (rb ^ 1) * 4);
        if constexpr (BFS) { if (t + 2 < NT) loadpf(sidx(t + 2)); }
        BARRIER();  // B2
    }

    if constexpr (BFS) {
        // export state (unscaled; pending max absorbed in combine's log|D1|)
        size_t base = (FWD ? EXPAF : EXPW) + (size_t)b * 4096;
        int row = tid >> 2, c0 = (tid & 3) * 16;
        *reinterpret_cast<short8*>(wsb + base + row * 64 + c0) =
            ldfrag(su + BPL(7) + (size_t)row * ST + c0);
        *reinterpret_cast<short8*>(wsb + base + row * 64 + c0 + 8) =
            ldfrag(su + BPL(7) + (size_t)row * ST + c0 + 8);
        if (tid == 0) wsf[FWD ? b : 64 + b] = accl;
    } else {
        // full-chain final site i=255
        const float* Mo128 = mps_out + (size_t)128 * 16384;
        float fv0 = inp[(255 * 64 + b) * 2], fv1 = inp[(255 * 64 + b) * 2 + 1];
        if (tid < 128) {
            int d2 = tid >> 1, jj = tid & 1;
            A0s[tid] = fv0 * Mo128[d2 * 256 + jj] + fv1 * Mo128[d2 * 256 + 2 + jj];
        }
        BARRIER();
        float part = 0.f;
#pragma unroll
        for (int n = 0; n < 16; n++) {
            int e = tid + 256 * n;
            int d2 = e >> 6, u = e & 63;
            part += b2f(su[BPL(7) + d2 * ST + u]) *
                    (A0s[2 * d2] * A0s[2 * u] + A0s[2 * d2 + 1] * A0s[2 * u + 1]);
        }
#pragma unroll
        for (int off = 32; off > 0; off >>= 1)
            part += __shfl_xor(part, off, 64);
        BARRIER();
        if ((tid & 63) == 0) bms[tid >> 6] = part;
        BARRIER();
        if (tid == 0) {
            float v = bms[0] + bms[1] + bms[2] + bms[3];
            wsf[b] = accl + logf(fabsf(v));
        }
    }
}

__global__ void proj_combine(const float* __restrict__ wsf, const ushort* __restrict__ wsb,
                             float* __restrict__ out, int n, int mode) {
    __shared__ float sred[8];
    const int b = blockIdx.x, tid = threadIdx.x;
    if (b >= n) return;
    if (!mode) {
        if (tid == 0) out[b] = wsf[b] - wsf[128];
        return;
    }
    float d1 = 0.f, d2 = 0.f;
#pragma unroll
    for (int q = 0; q < 16; q++) {
        int e = tid + 256 * q;
        d1 += b2f(wsb[EXPAF + (size_t)b * 4096 + e]) * b2f(wsb[EXPW + (size_t)b * 4096 + e]);
        d2 += b2f(wsb[EXPFW + e]) * b2f(wsb[EXPBW + e]);
    }
#pragma unroll
    for (int off = 32; off > 0; off >>= 1) {
        d1 += __shfl_xor(d1, off, 64);
        d2 += __shfl_xor(d2, off, 64);
    }
    if ((tid & 63) == 0) { sred[tid >> 6] = d1; sred[4 + (tid >> 6)] = d2; }
    __syncthreads();
    if (tid == 0) {
        float D1 = sred[0] + sred[1] + sred[2] + sred[3];
        float D2 = sred[4] + sred[5] + sred[6] + sred[7];
        out[b] = wsf[b] + wsf[64 + b] + logf(fabsf(D1)) -
                 (wsf[128] + wsf[129] + logf(fabsf(D2)));
    }
}

extern "C" void kernel_launch(void* const* d_in, const int* in_sizes, int n_in,
                              void* d_out, int out_size, void* d_ws, size_t ws_size,
                              hipStream_t stream) {
    const float* inp = (const float*)d_in[0];
    const float* mi  = (const float*)d_in[1];
    const float* mo  = (const float*)d_in[2];
    float* wsf = (float*)d_ws;
    ushort* wsb = (ushort*)((char*)d_ws + 1024);
    size_t need = 1024 + WS_U16_ALL * 2;
    int mode = (ws_size >= need) ? 1 : 0;
    if (mode) {
        preconv<<<dim3(256), dim3(256), 0, stream>>>(mi, mo, wsb);
        proj_chain<true><<<dim3(130), dim3(256), 0, stream>>>(inp, mi, mo, wsf, wsb);
    } else {
        proj_chain<false><<<dim3(130), dim3(256), 0, stream>>>(inp, mi, mo, wsf, wsb);
    }
    proj_combine<<<dim3(64), dim3(256), 0, stream>>>(wsf, wsb, (float*)d_out, out_size, mode);
}